// Round 1
// baseline (774.340 us; speedup 1.0000x reference)
//
#include <hip/hip_runtime.h>

#define NN_NODES 100000
#define NN_EDGES 50000
#define DD 128
#define NNZP 1600000
#define NT_SEG (NN_EDGES + NN_NODES)   // 150000 segments total (edges then nodes)

// ---------------- CSR build ----------------

__global__ void k_hist(const int* __restrict__ ninc, const int* __restrict__ einc,
                       int* __restrict__ cnt) {
  int i = blockIdx.x * blockDim.x + threadIdx.x;
  if (i >= NNZP) return;
  atomicAdd(&cnt[einc[i]], 1);
  atomicAdd(&cnt[NN_EDGES + ninc[i]], 1);
}

// per-block inclusive scan of cnt -> offs (partial), block totals -> blksum
__global__ void k_scanA(const int* __restrict__ cnt, int* __restrict__ offs,
                        int* __restrict__ blksum) {
  int i = blockIdx.x * 256 + threadIdx.x;
  int v = (i < NT_SEG) ? cnt[i] : 0;
  int lane = threadIdx.x & 63;
  int wid = threadIdx.x >> 6;
  int s = v;
  #pragma unroll
  for (int o = 1; o < 64; o <<= 1) {
    int t = __shfl_up(s, o, 64);
    if (lane >= o) s += t;
  }
  __shared__ int wsum[4];
  if (lane == 63) wsum[wid] = s;
  __syncthreads();
  int add = 0;
  for (int w2 = 0; w2 < wid; ++w2) add += wsum[w2];
  s += add;
  if (i < NT_SEG) offs[i] = s;                         // inclusive within block
  if (threadIdx.x == 255) blksum[blockIdx.x] = s;      // block total
}

// single-block exclusive scan of block sums (nb <= 1024)
__global__ void k_scanB(const int* __restrict__ blksum, int* __restrict__ blkoff, int nb) {
  int i = threadIdx.x;
  int v = (i < nb) ? blksum[i] : 0;
  int lane = i & 63, wid = i >> 6;
  int s = v;
  #pragma unroll
  for (int o = 1; o < 64; o <<= 1) {
    int t = __shfl_up(s, o, 64);
    if (lane >= o) s += t;
  }
  __shared__ int wsum[16];
  if (lane == 63) wsum[wid] = s;
  __syncthreads();
  int add = 0;
  for (int w2 = 0; w2 < wid; ++w2) add += wsum[w2];
  s += add;
  if (i < nb) blkoff[i] = s - v;                       // exclusive
}

// finalize exclusive offsets and init cursors
__global__ void k_scanC(const int* __restrict__ cnt, const int* __restrict__ blkoff,
                        int* __restrict__ offs, int* __restrict__ cur) {
  int i = blockIdx.x * 256 + threadIdx.x;
  if (i > NT_SEG) return;
  if (i == NT_SEG) { offs[i] = 2 * NNZP; return; }
  int e = offs[i] - cnt[i] + blkoff[i >> 8];
  offs[i] = e;
  cur[i] = e;
}

__global__ void k_fill(const int* __restrict__ ninc, const int* __restrict__ einc,
                       int* __restrict__ cur, int* __restrict__ list) {
  int i = blockIdx.x * blockDim.x + threadIdx.x;
  if (i >= NNZP) return;
  int n = ninc[i], e = einc[i];
  int pe = atomicAdd(&cur[e], 1);
  list[pe] = n;                     // node ids grouped by edge (positions [0, NNZ))
  int pn = atomicAdd(&cur[NN_EDGES + n], 1);
  list[pn] = e;                     // edge ids grouped by node (positions [NNZ, 2NNZ))
}

// ---------------- segment mean gather: one 32-lane group per segment ----------------

__global__ void k_agg(const float* __restrict__ src, float* __restrict__ dst,
                      const int* __restrict__ offs, const int* __restrict__ list,
                      int nseg, int segbase) {
  int g = (int)((blockIdx.x * blockDim.x + threadIdx.x) >> 5);
  int t = threadIdx.x & 31;
  if (g >= nseg) return;
  int b0 = offs[segbase + g];
  int b1 = offs[segbase + g + 1];
  int deg = b1 - b0;
  float4 acc = make_float4(0.f, 0.f, 0.f, 0.f);
  for (int chunk = 0; chunk < deg; chunk += 32) {
    int cnt = min(32, deg - chunk);
    int myidx = (t < cnt) ? list[b0 + chunk + t] : 0;
    #pragma unroll 4
    for (int m = 0; m < cnt; ++m) {
      int id = __shfl(myidx, m, 32);
      float4 v = reinterpret_cast<const float4*>(src + (size_t)id * DD)[t];
      acc.x += v.x; acc.y += v.y; acc.z += v.z; acc.w += v.w;
    }
  }
  float inv = 1.0f / fmaxf((float)deg, 1.0f);
  acc.x *= inv; acc.y *= inv; acc.z *= inv; acc.w *= inv;
  reinterpret_cast<float4*>(dst + (size_t)g * DD)[t] = acc;
}

// ---------------- dense fp32 GEMM: [M,128] @ [128,128] + bias(gated), opt relu ----------------
// In-place safe when A == C (block reads its own rows into LDS before writing them).

template<int RELU>
__global__ __launch_bounds__(256) void k_gemm128(
    const float* __restrict__ A, float* __restrict__ C,
    const float* __restrict__ Wg, const float* __restrict__ bias,
    const int* __restrict__ segoff, int M) {
  __shared__ float sW[DD * DD];        // 64 KB
  __shared__ float sA[DD * 132];       // 67.6 KB, pitch 132 -> conflict-free A reads
  const int tid = threadIdx.x;
  for (int i = tid; i < DD * DD / 4; i += 256)
    reinterpret_cast<float4*>(sW)[i] = reinterpret_cast<const float4*>(Wg)[i];
  const int tc = tid & 15;             // cols {4tc..4tc+3} and {64+4tc..64+4tc+3}
  const int tr = tid >> 4;             // rows r = tr + 16*i, i=0..7
  const int R = blockIdx.x * DD;
  const int rows = min(DD, M - R);
  for (int i = tid; i < DD * 32; i += 256) {
    int r = i >> 5, c4 = i & 31;
    float4 v = make_float4(0.f, 0.f, 0.f, 0.f);
    if (r < rows) v = reinterpret_cast<const float4*>(A + (size_t)(R + r) * DD)[c4];
    *reinterpret_cast<float4*>(&sA[r * 132 + c4 * 4]) = v;
  }
  __syncthreads();
  float acc[8][8];
  #pragma unroll
  for (int i = 0; i < 8; ++i)
    #pragma unroll
    for (int j = 0; j < 8; ++j) acc[i][j] = 0.f;
  #pragma unroll 2
  for (int k4 = 0; k4 < 32; ++k4) {
    float4 a[8];
    #pragma unroll
    for (int i = 0; i < 8; ++i)
      a[i] = *reinterpret_cast<const float4*>(&sA[(tr + 16 * i) * 132 + k4 * 4]);
    #pragma unroll
    for (int kk = 0; kk < 4; ++kk) {
      const float* wrow = &sW[(k4 * 4 + kk) * DD];
      float4 b0 = *reinterpret_cast<const float4*>(&wrow[4 * tc]);
      float4 b1 = *reinterpret_cast<const float4*>(&wrow[64 + 4 * tc]);
      #pragma unroll
      for (int i = 0; i < 8; ++i) {
        float av = (kk == 0) ? a[i].x : (kk == 1) ? a[i].y : (kk == 2) ? a[i].z : a[i].w;
        acc[i][0] += av * b0.x; acc[i][1] += av * b0.y;
        acc[i][2] += av * b0.z; acc[i][3] += av * b0.w;
        acc[i][4] += av * b1.x; acc[i][5] += av * b1.y;
        acc[i][6] += av * b1.z; acc[i][7] += av * b1.w;
      }
    }
  }
  float4 bias0 = reinterpret_cast<const float4*>(bias)[tc];
  float4 bias1 = reinterpret_cast<const float4*>(bias)[16 + tc];
  #pragma unroll
  for (int i = 0; i < 8; ++i) {
    int r = tr + 16 * i;
    if (r < rows) {
      int gr = R + r;
      float flag = (segoff[gr + 1] > segoff[gr]) ? 1.f : 0.f;
      float4 o0, o1;
      o0.x = acc[i][0] + bias0.x * flag;
      o0.y = acc[i][1] + bias0.y * flag;
      o0.z = acc[i][2] + bias0.z * flag;
      o0.w = acc[i][3] + bias0.w * flag;
      o1.x = acc[i][4] + bias1.x * flag;
      o1.y = acc[i][5] + bias1.y * flag;
      o1.z = acc[i][6] + bias1.z * flag;
      o1.w = acc[i][7] + bias1.w * flag;
      if (RELU) {
        o0.x = fmaxf(o0.x, 0.f); o0.y = fmaxf(o0.y, 0.f);
        o0.z = fmaxf(o0.z, 0.f); o0.w = fmaxf(o0.w, 0.f);
        o1.x = fmaxf(o1.x, 0.f); o1.y = fmaxf(o1.y, 0.f);
        o1.z = fmaxf(o1.z, 0.f); o1.w = fmaxf(o1.w, 0.f);
      }
      reinterpret_cast<float4*>(C + (size_t)gr * DD)[tc] = o0;
      reinterpret_cast<float4*>(C + (size_t)gr * DD)[16 + tc] = o1;
    }
  }
}

extern "C" void kernel_launch(void* const* d_in, const int* in_sizes, int n_in,
                              void* d_out, int out_size, void* d_ws, size_t ws_size,
                              hipStream_t stream) {
  const float* X  = (const float*)d_in[1];   // y: [N_NODES*D]
  const int*   inc = (const int*)d_in[2];    // incidence [2, NNZ]
  const float* W1 = (const float*)d_in[3];
  const float* b1 = (const float*)d_in[4];
  const float* W2 = (const float*)d_in[5];
  const float* b2 = (const float*)d_in[6];
  float* out = (float*)d_out;
  const int* ninc = inc;
  const int* einc = inc + NNZP;

  // workspace carve-up (~91.4 MB total)
  char* wsp = (char*)d_ws;
  float* buf1 = (float*)wsp;  wsp += (size_t)NN_EDGES * DD * sizeof(float);   // 25.6 MB: edge_raw -> edge_feat (in-place GEMM)
  float* buf2 = (float*)wsp;  wsp += (size_t)NN_NODES * DD * sizeof(float);   // 51.2 MB: node_raw
  int* cnt    = (int*)wsp;    wsp += (size_t)NT_SEG * sizeof(int);
  int* offs   = (int*)wsp;    wsp += (size_t)(NT_SEG + 1) * sizeof(int);
  int* cur    = (int*)wsp;    wsp += (size_t)NT_SEG * sizeof(int);
  int* blksum = (int*)wsp;    wsp += 1024 * sizeof(int);
  int* blkoff = (int*)wsp;    wsp += 1024 * sizeof(int);
  int* list   = (int*)wsp;    wsp += (size_t)(2 * NNZP) * sizeof(int);        // 12.8 MB

  hipMemsetAsync(cnt, 0, (size_t)NT_SEG * sizeof(int), stream);

  const int nbNNZ = (NNZP + 255) / 256;          // 6250
  k_hist<<<nbNNZ, 256, 0, stream>>>(ninc, einc, cnt);

  const int nbScan = (NT_SEG + 255) / 256;       // 586
  k_scanA<<<nbScan, 256, 0, stream>>>(cnt, offs, blksum);
  k_scanB<<<1, 1024, 0, stream>>>(blksum, blkoff, nbScan);
  const int nbScanC = (NT_SEG + 1 + 255) / 256;  // 587
  k_scanC<<<nbScanC, 256, 0, stream>>>(cnt, blkoff, offs, cur);

  k_fill<<<nbNNZ, 256, 0, stream>>>(ninc, einc, cur, list);

  // edge_raw[e] = mean_{n in e} X[n]
  k_agg<<<(NN_EDGES * 32 + 255) / 256, 256, 0, stream>>>(X, buf1, offs, list, NN_EDGES, 0);
  // edge_feat = edge_raw @ W1 + b1 (gated by deg>0), in-place
  k_gemm128<0><<<(NN_EDGES + DD - 1) / DD, 256, 0, stream>>>(buf1, buf1, W1, b1, offs, NN_EDGES);
  // node_raw[n] = mean_{e ni n} edge_feat[e]
  k_agg<<<(NN_NODES * 32 + 255) / 256, 256, 0, stream>>>(buf1, buf2, offs, list, NN_NODES, NN_EDGES);
  // out = relu(node_raw @ W2 + b2 (gated)), written straight to d_out
  k_gemm128<1><<<(NN_NODES + DD - 1) / DD, 256, 0, stream>>>(buf2, out, W2, b2, offs + NN_EDGES, NN_NODES);
}

// Round 2
// 450.756 us; speedup vs baseline: 1.7179x; 1.7179x over previous
//
#include <hip/hip_runtime.h>

#define NN_NODES 100000
#define NN_EDGES 50000
#define DD 128
#define NNZP 1600000
#define NT_SEG (NN_EDGES + NN_NODES)   // 150000 segments (edges first, then nodes)
#define TOTP (2 * NNZP)                // 3.2M (seg,val) pairs across both directions
#define BKT_SHIFT 9                    // 512 segments per bucket
#define NBKT ((NT_SEG + 511) / 512)    // 293
#define TILE 8192
#define SMAX 18432                     // max staged bucket size (edge buckets avg 16384)

// ---------- exclusive block scan over 512 ints, 512 threads ----------
__device__ __forceinline__ void block_excl_scan_512(const int* __restrict__ arr,
                                                    int* __restrict__ out,
                                                    int* __restrict__ wsum) {
  int t = threadIdx.x;
  int v = arr[t];
  int lane = t & 63, wid = t >> 6;
  int s = v;
  #pragma unroll
  for (int o = 1; o < 64; o <<= 1) {
    int u = __shfl_up(s, o, 64);
    if (lane >= o) s += u;
  }
  if (lane == 63) wsum[wid] = s;
  __syncthreads();
  int add = 0;
  for (int w = 0; w < wid; ++w) add += wsum[w];
  out[t] = s + add - v;               // exclusive prefix
}

// ---------- coarse bucket histogram ----------
__global__ void k_bhist(const int* __restrict__ ninc, const int* __restrict__ einc,
                        int* __restrict__ bktcnt) {
  __shared__ int h[512];
  for (int t = threadIdx.x; t < 512; t += blockDim.x) h[t] = 0;
  __syncthreads();
  int stride = gridDim.x * blockDim.x;
  for (int i = blockIdx.x * blockDim.x + threadIdx.x; i < TOTP; i += stride) {
    int seg = (i < NNZP) ? einc[i] : (NN_EDGES + ninc[i - NNZP]);
    atomicAdd(&h[seg >> BKT_SHIFT], 1);
  }
  __syncthreads();
  for (int t = threadIdx.x; t < NBKT; t += blockDim.x)
    if (h[t]) atomicAdd(&bktcnt[t], h[t]);
}

// ---------- bucket base scan (1 block, 512 threads) ----------
__global__ void k_bscan(const int* __restrict__ bktcnt, int* __restrict__ bktbase,
                        int* __restrict__ bktcur, int* __restrict__ offs) {
  __shared__ int arr[512], out[512], wsum[8];
  int t = threadIdx.x;
  arr[t] = (t < NBKT) ? bktcnt[t] : 0;
  __syncthreads();
  block_excl_scan_512(arr, out, wsum);
  __syncthreads();
  bktbase[t] = out[t];                // for t >= NBKT this is TOTP -> sentinel works
  bktcur[t] = out[t];
  if (t == 0) offs[NT_SEG] = TOTP;
}

// ---------- bin pairs into coarse buckets with coalesced run writes ----------
__global__ __launch_bounds__(512) void k_bin(const int* __restrict__ ninc,
                                             const int* __restrict__ einc,
                                             int* __restrict__ bktcur,
                                             int* __restrict__ bval,
                                             unsigned short* __restrict__ blow) {
  __shared__ int sval[TILE];
  __shared__ unsigned short slow[TILE], sbkt[TILE];
  __shared__ int bhist[512], bexcl[512], bcur[512], brun[512], wsum[8];
  const int t = threadIdx.x;
  const int i0 = blockIdx.x * TILE;
  const int V = min(TILE, TOTP - i0);
  bhist[t] = 0;
  __syncthreads();
  // pass 1: bucket histogram for this tile
  for (int e = t; e < V; e += 512) {
    int i = i0 + e;
    int seg = (i < NNZP) ? einc[i] : (NN_EDGES + ninc[i - NNZP]);
    atomicAdd(&bhist[seg >> BKT_SHIFT], 1);
  }
  __syncthreads();
  block_excl_scan_512(bhist, bexcl, wsum);
  __syncthreads();
  // reserve global runs, init local cursors
  if (t < NBKT && bhist[t] > 0) brun[t] = atomicAdd(&bktcur[t], bhist[t]);
  bcur[t] = bexcl[t];
  __syncthreads();
  // pass 2: stage tile reordered by bucket (re-read globals: L1/L2 hot)
  for (int e = t; e < V; e += 512) {
    int i = i0 + e;
    int seg, val;
    if (i < NNZP) { seg = einc[i]; val = ninc[i]; }
    else          { seg = NN_EDGES + ninc[i - NNZP]; val = einc[i - NNZP]; }
    int bk = seg >> BKT_SHIFT;
    int slot = atomicAdd(&bcur[bk], 1);
    sval[slot] = val;
    slow[slot] = (unsigned short)(seg & 511);
    sbkt[slot] = (unsigned short)bk;
  }
  __syncthreads();
  // pass 3: linear coalesced write-out (runs of ~40-90 elems per bucket)
  for (int e = t; e < V; e += 512) {
    int bk = sbkt[e];
    int gpos = brun[bk] + (e - bexcl[bk]);
    bval[gpos] = sval[e];
    blow[gpos] = slow[e];
  }
}

// ---------- per-bucket placement: builds offs + final sorted list ----------
__global__ __launch_bounds__(512) void k_place(const int* __restrict__ bktbase,
                                               const int* __restrict__ bval,
                                               const unsigned short* __restrict__ blow,
                                               int* __restrict__ offs,
                                               int* __restrict__ list) {
  __shared__ int shist[512], sexcl[512], scur[512], wsum[8];
  __shared__ int stage[SMAX];
  const int b = blockIdx.x;
  const int t = threadIdx.x;
  const int base = bktbase[b];
  const int s = bktbase[b + 1] - base;
  shist[t] = 0;
  __syncthreads();
  for (int e = t; e < s; e += 512) atomicAdd(&shist[blow[base + e]], 1);
  __syncthreads();
  block_excl_scan_512(shist, sexcl, wsum);
  __syncthreads();
  int seg = (b << BKT_SHIFT) + t;
  if (seg < NT_SEG) offs[seg] = base + sexcl[t];
  scur[t] = sexcl[t];
  __syncthreads();
  if (s <= SMAX) {
    for (int e = t; e < s; e += 512) {
      int slot = atomicAdd(&scur[blow[base + e]], 1);
      stage[slot] = bval[base + e];
    }
    __syncthreads();
    for (int e = t; e < s; e += 512) list[base + e] = stage[e];
  } else {  // overflow fallback (statistically unreachable): direct scatter
    for (int e = t; e < s; e += 512) {
      int r = atomicAdd(&scur[blow[base + e]], 1);
      list[base + r] = bval[base + e];
    }
  }
}

// ---------- segment mean gather: one 32-lane group per segment ----------
__global__ void k_agg(const float* __restrict__ src, float* __restrict__ dst,
                      const int* __restrict__ offs, const int* __restrict__ list,
                      int nseg, int segbase) {
  int g = (int)((blockIdx.x * blockDim.x + threadIdx.x) >> 5);
  int t = threadIdx.x & 31;
  if (g >= nseg) return;
  int b0 = offs[segbase + g];
  int b1 = offs[segbase + g + 1];
  int deg = b1 - b0;
  float4 acc = make_float4(0.f, 0.f, 0.f, 0.f);
  for (int chunk = 0; chunk < deg; chunk += 32) {
    int cnt = min(32, deg - chunk);
    int myidx = (t < cnt) ? list[b0 + chunk + t] : 0;
    #pragma unroll 4
    for (int m = 0; m < cnt; ++m) {
      int id = __shfl(myidx, m, 32);
      float4 v = reinterpret_cast<const float4*>(src + (size_t)id * DD)[t];
      acc.x += v.x; acc.y += v.y; acc.z += v.z; acc.w += v.w;
    }
  }
  float inv = 1.0f / fmaxf((float)deg, 1.0f);
  acc.x *= inv; acc.y *= inv; acc.z *= inv; acc.w *= inv;
  reinterpret_cast<float4*>(dst + (size_t)g * DD)[t] = acc;
}

// ---------- dense fp32 GEMM: [M,128] @ [128,128] + gated bias, opt relu ----------
template<int RELU>
__global__ __launch_bounds__(256) void k_gemm128(
    const float* __restrict__ A, float* __restrict__ C,
    const float* __restrict__ Wg, const float* __restrict__ bias,
    const int* __restrict__ segoff, int M) {
  __shared__ float sW[DD * DD];
  __shared__ float sA[DD * 132];
  const int tid = threadIdx.x;
  for (int i = tid; i < DD * DD / 4; i += 256)
    reinterpret_cast<float4*>(sW)[i] = reinterpret_cast<const float4*>(Wg)[i];
  const int tc = tid & 15;
  const int tr = tid >> 4;
  const int R = blockIdx.x * DD;
  const int rows = min(DD, M - R);
  for (int i = tid; i < DD * 32; i += 256) {
    int r = i >> 5, c4 = i & 31;
    float4 v = make_float4(0.f, 0.f, 0.f, 0.f);
    if (r < rows) v = reinterpret_cast<const float4*>(A + (size_t)(R + r) * DD)[c4];
    *reinterpret_cast<float4*>(&sA[r * 132 + c4 * 4]) = v;
  }
  __syncthreads();
  float acc[8][8];
  #pragma unroll
  for (int i = 0; i < 8; ++i)
    #pragma unroll
    for (int j = 0; j < 8; ++j) acc[i][j] = 0.f;
  #pragma unroll 2
  for (int k4 = 0; k4 < 32; ++k4) {
    float4 a[8];
    #pragma unroll
    for (int i = 0; i < 8; ++i)
      a[i] = *reinterpret_cast<const float4*>(&sA[(tr + 16 * i) * 132 + k4 * 4]);
    #pragma unroll
    for (int kk = 0; kk < 4; ++kk) {
      const float* wrow = &sW[(k4 * 4 + kk) * DD];
      float4 b0 = *reinterpret_cast<const float4*>(&wrow[4 * tc]);
      float4 b1 = *reinterpret_cast<const float4*>(&wrow[64 + 4 * tc]);
      #pragma unroll
      for (int i = 0; i < 8; ++i) {
        float av = (kk == 0) ? a[i].x : (kk == 1) ? a[i].y : (kk == 2) ? a[i].z : a[i].w;
        acc[i][0] += av * b0.x; acc[i][1] += av * b0.y;
        acc[i][2] += av * b0.z; acc[i][3] += av * b0.w;
        acc[i][4] += av * b1.x; acc[i][5] += av * b1.y;
        acc[i][6] += av * b1.z; acc[i][7] += av * b1.w;
      }
    }
  }
  float4 bias0 = reinterpret_cast<const float4*>(bias)[tc];
  float4 bias1 = reinterpret_cast<const float4*>(bias)[16 + tc];
  #pragma unroll
  for (int i = 0; i < 8; ++i) {
    int r = tr + 16 * i;
    if (r < rows) {
      int gr = R + r;
      float flag = (segoff[gr + 1] > segoff[gr]) ? 1.f : 0.f;
      float4 o0, o1;
      o0.x = acc[i][0] + bias0.x * flag;
      o0.y = acc[i][1] + bias0.y * flag;
      o0.z = acc[i][2] + bias0.z * flag;
      o0.w = acc[i][3] + bias0.w * flag;
      o1.x = acc[i][4] + bias1.x * flag;
      o1.y = acc[i][5] + bias1.y * flag;
      o1.z = acc[i][6] + bias1.z * flag;
      o1.w = acc[i][7] + bias1.w * flag;
      if (RELU) {
        o0.x = fmaxf(o0.x, 0.f); o0.y = fmaxf(o0.y, 0.f);
        o0.z = fmaxf(o0.z, 0.f); o0.w = fmaxf(o0.w, 0.f);
        o1.x = fmaxf(o1.x, 0.f); o1.y = fmaxf(o1.y, 0.f);
        o1.z = fmaxf(o1.z, 0.f); o1.w = fmaxf(o1.w, 0.f);
      }
      reinterpret_cast<float4*>(C + (size_t)gr * DD)[tc] = o0;
      reinterpret_cast<float4*>(C + (size_t)gr * DD)[16 + tc] = o1;
    }
  }
}

extern "C" void kernel_launch(void* const* d_in, const int* in_sizes, int n_in,
                              void* d_out, int out_size, void* d_ws, size_t ws_size,
                              hipStream_t stream) {
  const float* X   = (const float*)d_in[1];
  const int*   inc = (const int*)d_in[2];
  const float* W1  = (const float*)d_in[3];
  const float* b1  = (const float*)d_in[4];
  const float* W2  = (const float*)d_in[5];
  const float* b2  = (const float*)d_in[6];
  float* out = (float*)d_out;
  const int* ninc = inc;
  const int* einc = inc + NNZP;

  // workspace carve-up (~90 MB)
  char* wsp = (char*)d_ws;
  float* buf1 = (float*)wsp;  wsp += (size_t)NN_EDGES * DD * sizeof(float);   // 25.6 MB
  float* buf2 = (float*)wsp;  wsp += (size_t)NN_NODES * DD * sizeof(float);   // 51.2 MB
  int* offs    = (int*)wsp;   wsp += (size_t)(NT_SEG + 1) * sizeof(int);
  int* list    = (int*)wsp;   wsp += (size_t)TOTP * sizeof(int);              // 12.8 MB
  int* bktcnt  = (int*)wsp;   wsp += 512 * sizeof(int);
  int* bktbase = (int*)wsp;   wsp += 512 * sizeof(int);
  int* bktcur  = (int*)wsp;   wsp += 512 * sizeof(int);
  // binned pairs aliased into buf2 (dead before buf2 is first written)
  int* bval = (int*)buf2;                                        // 12.8 MB
  unsigned short* blow = (unsigned short*)((char*)buf2 + (size_t)TOTP * sizeof(int)); // 6.4 MB

  hipMemsetAsync(bktcnt, 0, 512 * sizeof(int), stream);

  k_bhist<<<512, 256, 0, stream>>>(ninc, einc, bktcnt);
  k_bscan<<<1, 512, 0, stream>>>(bktcnt, bktbase, bktcur, offs);
  k_bin<<<(TOTP + TILE - 1) / TILE, 512, 0, stream>>>(ninc, einc, bktcur, bval, blow);
  k_place<<<NBKT, 512, 0, stream>>>(bktbase, bval, blow, offs, list);

  // edge_raw[e] = mean_{n in e} X[n]
  k_agg<<<(NN_EDGES * 32 + 255) / 256, 256, 0, stream>>>(X, buf1, offs, list, NN_EDGES, 0);
  // edge_feat = edge_raw @ W1 + b1 (deg-gated), in-place
  k_gemm128<0><<<(NN_EDGES + DD - 1) / DD, 256, 0, stream>>>(buf1, buf1, W1, b1, offs, NN_EDGES);
  // node_raw[n] = mean_{e ni n} edge_feat[e]
  k_agg<<<(NN_NODES * 32 + 255) / 256, 256, 0, stream>>>(buf1, buf2, offs, list, NN_NODES, NN_EDGES);
  // out = relu(node_raw @ W2 + b2 (deg-gated))
  k_gemm128<1><<<(NN_NODES + DD - 1) / DD, 256, 0, stream>>>(buf2, out, W2, b2, offs + NN_EDGES, NN_NODES);
}

// Round 3
// 375.672 us; speedup vs baseline: 2.0612x; 1.1999x over previous
//
#include <hip/hip_runtime.h>

#define NN_NODES 100000
#define NN_EDGES 50000
#define DD 128
#define NNZP 1600000
#define NT_SEG (NN_EDGES + NN_NODES)   // 150000 segments (edges first, then nodes)
#define TOTP (2 * NNZP)                // 3.2M (seg,val) pairs across both directions
#define BKT_SHIFT 9                    // 512 segments per bucket
#define NBKT ((NT_SEG + 511) / 512)    // 293
#define TILE 8192
#define SMAX 18432

typedef unsigned int uint;
typedef unsigned short ushort;

__device__ __forceinline__ float bf_lo(uint u) {
  union { uint i; float f; } c; c.i = u << 16; return c.f;
}
__device__ __forceinline__ float bf_hi(uint u) {
  union { uint i; float f; } c; c.i = u & 0xffff0000u; return c.f;
}
__device__ __forceinline__ ushort f2bf(float f) {   // round-to-nearest-even
  union { float f; uint i; } c; c.f = f;
  uint r = c.i + 0x7fffu + ((c.i >> 16) & 1u);
  return (ushort)(r >> 16);
}

// ---------- exclusive block scan over 512 ints, 512 threads ----------
__device__ __forceinline__ void block_excl_scan_512(const int* __restrict__ arr,
                                                    int* __restrict__ out,
                                                    int* __restrict__ wsum) {
  int t = threadIdx.x;
  int v = arr[t];
  int lane = t & 63, wid = t >> 6;
  int s = v;
  #pragma unroll
  for (int o = 1; o < 64; o <<= 1) {
    int u = __shfl_up(s, o, 64);
    if (lane >= o) s += u;
  }
  if (lane == 63) wsum[wid] = s;
  __syncthreads();
  int add = 0;
  for (int w = 0; w < wid; ++w) add += wsum[w];
  out[t] = s + add - v;
}

// ---------- coarse bucket histogram ----------
__global__ void k_bhist(const int* __restrict__ ninc, const int* __restrict__ einc,
                        int* __restrict__ bktcnt) {
  __shared__ int h[512];
  for (int t = threadIdx.x; t < 512; t += blockDim.x) h[t] = 0;
  __syncthreads();
  int stride = gridDim.x * blockDim.x;
  for (int i = blockIdx.x * blockDim.x + threadIdx.x; i < TOTP; i += stride) {
    int seg = (i < NNZP) ? einc[i] : (NN_EDGES + ninc[i - NNZP]);
    atomicAdd(&h[seg >> BKT_SHIFT], 1);
  }
  __syncthreads();
  for (int t = threadIdx.x; t < NBKT; t += blockDim.x)
    if (h[t]) atomicAdd(&bktcnt[t], h[t]);
}

// ---------- bucket base scan (1 block, 512 threads) ----------
__global__ void k_bscan(const int* __restrict__ bktcnt, int* __restrict__ bktbase,
                        int* __restrict__ bktcur, int* __restrict__ offs) {
  __shared__ int arr[512], out[512], wsum[8];
  int t = threadIdx.x;
  arr[t] = (t < NBKT) ? bktcnt[t] : 0;
  __syncthreads();
  block_excl_scan_512(arr, out, wsum);
  __syncthreads();
  bktbase[t] = out[t];
  bktcur[t] = out[t];
  if (t == 0) offs[NT_SEG] = TOTP;
}

// ---------- bin pairs into coarse buckets with coalesced run writes ----------
__global__ __launch_bounds__(512) void k_bin(const int* __restrict__ ninc,
                                             const int* __restrict__ einc,
                                             int* __restrict__ bktcur,
                                             int* __restrict__ bval,
                                             ushort* __restrict__ blow) {
  __shared__ int sval[TILE];
  __shared__ ushort slow[TILE], sbkt[TILE];
  __shared__ int bhist[512], bexcl[512], bcur[512], brun[512], wsum[8];
  const int t = threadIdx.x;
  const int i0 = blockIdx.x * TILE;
  const int V = min(TILE, TOTP - i0);
  bhist[t] = 0;
  __syncthreads();
  for (int e = t; e < V; e += 512) {
    int i = i0 + e;
    int seg = (i < NNZP) ? einc[i] : (NN_EDGES + ninc[i - NNZP]);
    atomicAdd(&bhist[seg >> BKT_SHIFT], 1);
  }
  __syncthreads();
  block_excl_scan_512(bhist, bexcl, wsum);
  __syncthreads();
  if (t < NBKT && bhist[t] > 0) brun[t] = atomicAdd(&bktcur[t], bhist[t]);
  bcur[t] = bexcl[t];
  __syncthreads();
  for (int e = t; e < V; e += 512) {
    int i = i0 + e;
    int seg, val;
    if (i < NNZP) { seg = einc[i]; val = ninc[i]; }
    else          { seg = NN_EDGES + ninc[i - NNZP]; val = einc[i - NNZP]; }
    int bk = seg >> BKT_SHIFT;
    int slot = atomicAdd(&bcur[bk], 1);
    sval[slot] = val;
    slow[slot] = (ushort)(seg & 511);
    sbkt[slot] = (ushort)bk;
  }
  __syncthreads();
  for (int e = t; e < V; e += 512) {
    int bk = sbkt[e];
    int gpos = brun[bk] + (e - bexcl[bk]);
    bval[gpos] = sval[e];
    blow[gpos] = slow[e];
  }
}

// ---------- per-bucket placement: builds offs + final sorted list ----------
__global__ __launch_bounds__(512) void k_place(const int* __restrict__ bktbase,
                                               const int* __restrict__ bval,
                                               const ushort* __restrict__ blow,
                                               int* __restrict__ offs,
                                               int* __restrict__ list) {
  __shared__ int shist[512], sexcl[512], scur[512], wsum[8];
  __shared__ int stage[SMAX];
  const int b = blockIdx.x;
  const int t = threadIdx.x;
  const int base = bktbase[b];
  const int s = bktbase[b + 1] - base;
  shist[t] = 0;
  __syncthreads();
  for (int e = t; e < s; e += 512) atomicAdd(&shist[blow[base + e]], 1);
  __syncthreads();
  block_excl_scan_512(shist, sexcl, wsum);
  __syncthreads();
  int seg = (b << BKT_SHIFT) + t;
  if (seg < NT_SEG) offs[seg] = base + sexcl[t];
  scur[t] = sexcl[t];
  __syncthreads();
  if (s <= SMAX) {
    for (int e = t; e < s; e += 512) {
      int slot = atomicAdd(&scur[blow[base + e]], 1);
      stage[slot] = bval[base + e];
    }
    __syncthreads();
    for (int e = t; e < s; e += 512) list[base + e] = stage[e];
  } else {
    for (int e = t; e < s; e += 512) {
      int r = atomicAdd(&scur[blow[base + e]], 1);
      list[base + r] = bval[base + e];
    }
  }
}

// ---------- fp32 -> bf16 bulk convert ----------
__global__ void k_cvt(const float* __restrict__ src, ushort* __restrict__ dst, int n4) {
  int stride = gridDim.x * blockDim.x;
  for (int i = blockIdx.x * blockDim.x + threadIdx.x; i < n4; i += stride) {
    float4 v = reinterpret_cast<const float4*>(src)[i];
    ushort4 o;
    o.x = f2bf(v.x); o.y = f2bf(v.y); o.z = f2bf(v.z); o.w = f2bf(v.w);
    reinterpret_cast<ushort4*>(dst)[i] = o;
  }
}

// ---------- segment mean gather from bf16 rows: 32-lane group per segment ----------
// DSTBF: 1 -> write bf16 row, 0 -> write fp32 row
template<int DSTBF>
__global__ void k_agg(const ushort* __restrict__ src, void* __restrict__ dstv,
                      const int* __restrict__ offs, const int* __restrict__ list,
                      int nseg, int segbase) {
  int g = (int)((blockIdx.x * blockDim.x + threadIdx.x) >> 5);
  int t = threadIdx.x & 31;
  if (g >= nseg) return;
  int b0 = offs[segbase + g];
  int b1 = offs[segbase + g + 1];
  int deg = b1 - b0;
  float4 acc = make_float4(0.f, 0.f, 0.f, 0.f);
  for (int chunk = 0; chunk < deg; chunk += 32) {
    int cnt = min(32, deg - chunk);
    int myidx = (t < cnt) ? list[b0 + chunk + t] : 0;
    #pragma unroll 8
    for (int m = 0; m < cnt; ++m) {
      int id = __shfl(myidx, m, 32);
      uint2 v = reinterpret_cast<const uint2*>(src + (size_t)id * DD)[t];
      acc.x += bf_lo(v.x); acc.y += bf_hi(v.x);
      acc.z += bf_lo(v.y); acc.w += bf_hi(v.y);
    }
  }
  float inv = 1.0f / fmaxf((float)deg, 1.0f);
  acc.x *= inv; acc.y *= inv; acc.z *= inv; acc.w *= inv;
  if (DSTBF) {
    uint2 o;
    o.x = (uint)f2bf(acc.x) | ((uint)f2bf(acc.y) << 16);
    o.y = (uint)f2bf(acc.z) | ((uint)f2bf(acc.w) << 16);
    reinterpret_cast<uint2*>(dstv)[(size_t)g * 32 + t] = o;
  } else {
    reinterpret_cast<float4*>(dstv)[(size_t)g * 32 + t] = acc;
  }
}

// ---------- dense GEMM: [M,128] @ [128,128] + gated bias, opt relu ----------
// ABF16: A rows are bf16; CBF16: write C rows as bf16. In-place safe (A==C).
template<int RELU, int ABF16, int CBF16>
__global__ __launch_bounds__(256) void k_gemm128(
    const void* __restrict__ Av, void* __restrict__ Cv,
    const float* __restrict__ Wg, const float* __restrict__ bias,
    const int* __restrict__ segoff, int M) {
  __shared__ float sW[DD * DD];
  __shared__ float sA[DD * 132];
  const int tid = threadIdx.x;
  for (int i = tid; i < DD * DD / 4; i += 256)
    reinterpret_cast<float4*>(sW)[i] = reinterpret_cast<const float4*>(Wg)[i];
  const int tc = tid & 15;
  const int tr = tid >> 4;
  const int R = blockIdx.x * DD;
  const int rows = min(DD, M - R);
  if (ABF16) {
    const ushort* A = (const ushort*)Av;
    for (int i = tid; i < DD * 16; i += 256) {        // 16B (8 elems) per step
      int r = i >> 4, c8 = i & 15;
      float f[8];
      if (r < rows) {
        uint4 v = reinterpret_cast<const uint4*>(A + (size_t)(R + r) * DD)[c8];
        f[0] = bf_lo(v.x); f[1] = bf_hi(v.x); f[2] = bf_lo(v.y); f[3] = bf_hi(v.y);
        f[4] = bf_lo(v.z); f[5] = bf_hi(v.z); f[6] = bf_lo(v.w); f[7] = bf_hi(v.w);
      } else {
        #pragma unroll
        for (int j = 0; j < 8; ++j) f[j] = 0.f;
      }
      float* p = &sA[r * 132 + c8 * 8];
      *reinterpret_cast<float4*>(p)     = make_float4(f[0], f[1], f[2], f[3]);
      *reinterpret_cast<float4*>(p + 4) = make_float4(f[4], f[5], f[6], f[7]);
    }
  } else {
    const float* A = (const float*)Av;
    for (int i = tid; i < DD * 32; i += 256) {
      int r = i >> 5, c4 = i & 31;
      float4 v = make_float4(0.f, 0.f, 0.f, 0.f);
      if (r < rows) v = reinterpret_cast<const float4*>(A + (size_t)(R + r) * DD)[c4];
      *reinterpret_cast<float4*>(&sA[r * 132 + c4 * 4]) = v;
    }
  }
  __syncthreads();
  float acc[8][8];
  #pragma unroll
  for (int i = 0; i < 8; ++i)
    #pragma unroll
    for (int j = 0; j < 8; ++j) acc[i][j] = 0.f;
  #pragma unroll 2
  for (int k4 = 0; k4 < 32; ++k4) {
    float4 a[8];
    #pragma unroll
    for (int i = 0; i < 8; ++i)
      a[i] = *reinterpret_cast<const float4*>(&sA[(tr + 16 * i) * 132 + k4 * 4]);
    #pragma unroll
    for (int kk = 0; kk < 4; ++kk) {
      const float* wrow = &sW[(k4 * 4 + kk) * DD];
      float4 b0 = *reinterpret_cast<const float4*>(&wrow[4 * tc]);
      float4 b1 = *reinterpret_cast<const float4*>(&wrow[64 + 4 * tc]);
      #pragma unroll
      for (int i = 0; i < 8; ++i) {
        float av = (kk == 0) ? a[i].x : (kk == 1) ? a[i].y : (kk == 2) ? a[i].z : a[i].w;
        acc[i][0] += av * b0.x; acc[i][1] += av * b0.y;
        acc[i][2] += av * b0.z; acc[i][3] += av * b0.w;
        acc[i][4] += av * b1.x; acc[i][5] += av * b1.y;
        acc[i][6] += av * b1.z; acc[i][7] += av * b1.w;
      }
    }
  }
  float4 bias0 = reinterpret_cast<const float4*>(bias)[tc];
  float4 bias1 = reinterpret_cast<const float4*>(bias)[16 + tc];
  #pragma unroll
  for (int i = 0; i < 8; ++i) {
    int r = tr + 16 * i;
    if (r < rows) {
      int gr = R + r;
      float flag = (segoff[gr + 1] > segoff[gr]) ? 1.f : 0.f;
      float4 o0, o1;
      o0.x = acc[i][0] + bias0.x * flag;
      o0.y = acc[i][1] + bias0.y * flag;
      o0.z = acc[i][2] + bias0.z * flag;
      o0.w = acc[i][3] + bias0.w * flag;
      o1.x = acc[i][4] + bias1.x * flag;
      o1.y = acc[i][5] + bias1.y * flag;
      o1.z = acc[i][6] + bias1.z * flag;
      o1.w = acc[i][7] + bias1.w * flag;
      if (RELU) {
        o0.x = fmaxf(o0.x, 0.f); o0.y = fmaxf(o0.y, 0.f);
        o0.z = fmaxf(o0.z, 0.f); o0.w = fmaxf(o0.w, 0.f);
        o1.x = fmaxf(o1.x, 0.f); o1.y = fmaxf(o1.y, 0.f);
        o1.z = fmaxf(o1.z, 0.f); o1.w = fmaxf(o1.w, 0.f);
      }
      if (CBF16) {
        ushort* C = (ushort*)Cv;
        uint2* row = reinterpret_cast<uint2*>(C + (size_t)gr * DD);
        uint2 w0, w1;
        w0.x = (uint)f2bf(o0.x) | ((uint)f2bf(o0.y) << 16);
        w0.y = (uint)f2bf(o0.z) | ((uint)f2bf(o0.w) << 16);
        w1.x = (uint)f2bf(o1.x) | ((uint)f2bf(o1.y) << 16);
        w1.y = (uint)f2bf(o1.z) | ((uint)f2bf(o1.w) << 16);
        row[tc] = w0;
        row[16 + tc] = w1;
      } else {
        float* C = (float*)Cv;
        reinterpret_cast<float4*>(C + (size_t)gr * DD)[tc] = o0;
        reinterpret_cast<float4*>(C + (size_t)gr * DD)[16 + tc] = o1;
      }
    }
  }
}

extern "C" void kernel_launch(void* const* d_in, const int* in_sizes, int n_in,
                              void* d_out, int out_size, void* d_ws, size_t ws_size,
                              hipStream_t stream) {
  const float* X   = (const float*)d_in[1];
  const int*   inc = (const int*)d_in[2];
  const float* W1  = (const float*)d_in[3];
  const float* b1  = (const float*)d_in[4];
  const float* W2  = (const float*)d_in[5];
  const float* b2  = (const float*)d_in[6];
  float* out = (float*)d_out;
  const int* ninc = inc;
  const int* einc = inc + NNZP;

  // workspace carve-up (~77.5 MB)
  char* wsp = (char*)d_ws;
  ushort* bufE = (ushort*)wsp; wsp += (size_t)NN_EDGES * DD * sizeof(ushort);  // 12.8 MB bf16 edge buf (in-place GEMM1)
  float* buf2  = (float*)wsp;  wsp += (size_t)NN_NODES * DD * sizeof(float);   // 51.2 MB fp32 node_raw
  int* offs    = (int*)wsp;    wsp += (size_t)(NT_SEG + 1) * sizeof(int);
  int* list    = (int*)wsp;    wsp += (size_t)TOTP * sizeof(int);              // 12.8 MB
  int* bktcnt  = (int*)wsp;    wsp += 512 * sizeof(int);
  int* bktbase = (int*)wsp;    wsp += 512 * sizeof(int);
  int* bktcur  = (int*)wsp;    wsp += 512 * sizeof(int);
  // aliases inside buf2 (all dead before agg2 writes node_raw):
  int* bval = (int*)buf2;                                                      // [0, 12.8 MB)
  ushort* blow = (ushort*)((char*)buf2 + (size_t)TOTP * sizeof(int));          // [12.8, 19.2 MB)
  ushort* Xb = (ushort*)((char*)buf2 + (size_t)NN_EDGES * DD * sizeof(float)); // [25.6, 51.2 MB)

  hipMemsetAsync(bktcnt, 0, 512 * sizeof(int), stream);

  k_bhist<<<512, 256, 0, stream>>>(ninc, einc, bktcnt);
  k_bscan<<<1, 512, 0, stream>>>(bktcnt, bktbase, bktcur, offs);
  k_bin<<<(TOTP + TILE - 1) / TILE, 512, 0, stream>>>(ninc, einc, bktcur, bval, blow);
  k_place<<<NBKT, 512, 0, stream>>>(bktbase, bval, blow, offs, list);

  // X -> bf16 (12.8M elems, 3.2M float4s)
  k_cvt<<<2048, 256, 0, stream>>>(X, Xb, NN_NODES * DD / 4);

  // edge_raw[e] = mean_{n in e} Xb[n]  (bf16 out)
  k_agg<1><<<(NN_EDGES * 32 + 255) / 256, 256, 0, stream>>>(Xb, bufE, offs, list, NN_EDGES, 0);
  // edge_feat = edge_raw @ W1 + b1 (deg-gated), in-place bf16
  k_gemm128<0, 1, 1><<<(NN_EDGES + DD - 1) / DD, 256, 0, stream>>>(bufE, bufE, W1, b1, offs, NN_EDGES);
  // node_raw[n] = mean_{e ni n} edge_feat[e]  (fp32 out)
  k_agg<0><<<(NN_NODES * 32 + 255) / 256, 256, 0, stream>>>(bufE, buf2, offs, list, NN_NODES, NN_EDGES);
  // out = relu(node_raw @ W2 + b2 (deg-gated))
  k_gemm128<1, 0, 0><<<(NN_NODES + DD - 1) / DD, 256, 0, stream>>>(buf2, out, W2, b2, offs + NN_EDGES, NN_NODES);
}

// Round 4
// 249.804 us; speedup vs baseline: 3.0998x; 1.5039x over previous
//
#include <hip/hip_runtime.h>

#define NN_NODES 100000
#define NN_EDGES 50000
#define DD 128
#define NNZP 1600000
#define NT_SEG (NN_EDGES + NN_NODES)   // 150000 segments (edges first, then nodes)
#define TOTP (2 * NNZP)                // 3.2M (seg,val) pairs across both directions
#define BKT_SHIFT 9                    // 512 segments per bucket
#define NBKT ((NT_SEG + 511) / 512)    // 293
#define TILE 8192
#define SMAX 18432

typedef unsigned int uint;
typedef unsigned short ushort;
typedef __attribute__((ext_vector_type(8))) short bf16x8;
typedef __attribute__((ext_vector_type(4))) float f32x4;

__device__ __forceinline__ float bf_lo(uint u) {
  union { uint i; float f; } c; c.i = u << 16; return c.f;
}
__device__ __forceinline__ float bf_hi(uint u) {
  union { uint i; float f; } c; c.i = u & 0xffff0000u; return c.f;
}
__device__ __forceinline__ ushort f2bf(float f) {   // round-to-nearest-even
  union { float f; uint i; } c; c.f = f;
  uint r = c.i + 0x7fffu + ((c.i >> 16) & 1u);
  return (ushort)(r >> 16);
}

// ---------- exclusive block scan over 512 ints, 512 threads ----------
__device__ __forceinline__ void block_excl_scan_512(const int* __restrict__ arr,
                                                    int* __restrict__ out,
                                                    int* __restrict__ wsum) {
  int t = threadIdx.x;
  int v = arr[t];
  int lane = t & 63, wid = t >> 6;
  int s = v;
  #pragma unroll
  for (int o = 1; o < 64; o <<= 1) {
    int u = __shfl_up(s, o, 64);
    if (lane >= o) s += u;
  }
  if (lane == 63) wsum[wid] = s;
  __syncthreads();
  int add = 0;
  for (int w = 0; w < wid; ++w) add += wsum[w];
  out[t] = s + add - v;
}

// ---------- coarse bucket histogram ----------
__global__ void k_bhist(const int* __restrict__ ninc, const int* __restrict__ einc,
                        int* __restrict__ bktcnt) {
  __shared__ int h[512];
  for (int t = threadIdx.x; t < 512; t += blockDim.x) h[t] = 0;
  __syncthreads();
  int stride = gridDim.x * blockDim.x;
  for (int i = blockIdx.x * blockDim.x + threadIdx.x; i < TOTP; i += stride) {
    int seg = (i < NNZP) ? einc[i] : (NN_EDGES + ninc[i - NNZP]);
    atomicAdd(&h[seg >> BKT_SHIFT], 1);
  }
  __syncthreads();
  for (int t = threadIdx.x; t < NBKT; t += blockDim.x)
    if (h[t]) atomicAdd(&bktcnt[t], h[t]);
}

// ---------- bucket base scan (1 block, 512 threads) ----------
__global__ void k_bscan(const int* __restrict__ bktcnt, int* __restrict__ bktbase,
                        int* __restrict__ bktcur, int* __restrict__ offs) {
  __shared__ int arr[512], out[512], wsum[8];
  int t = threadIdx.x;
  arr[t] = (t < NBKT) ? bktcnt[t] : 0;
  __syncthreads();
  block_excl_scan_512(arr, out, wsum);
  __syncthreads();
  bktbase[t] = out[t];
  bktcur[t] = out[t];
  if (t == 0) offs[NT_SEG] = TOTP;
}

// ---------- bin pairs into coarse buckets with coalesced run writes ----------
__global__ __launch_bounds__(512) void k_bin(const int* __restrict__ ninc,
                                             const int* __restrict__ einc,
                                             int* __restrict__ bktcur,
                                             int* __restrict__ bval,
                                             ushort* __restrict__ blow) {
  __shared__ int sval[TILE];
  __shared__ ushort slow[TILE], sbkt[TILE];
  __shared__ int bhist[512], bexcl[512], bcur[512], brun[512], wsum[8];
  const int t = threadIdx.x;
  const int i0 = blockIdx.x * TILE;
  const int V = min(TILE, TOTP - i0);
  bhist[t] = 0;
  __syncthreads();
  for (int e = t; e < V; e += 512) {
    int i = i0 + e;
    int seg = (i < NNZP) ? einc[i] : (NN_EDGES + ninc[i - NNZP]);
    atomicAdd(&bhist[seg >> BKT_SHIFT], 1);
  }
  __syncthreads();
  block_excl_scan_512(bhist, bexcl, wsum);
  __syncthreads();
  if (t < NBKT && bhist[t] > 0) brun[t] = atomicAdd(&bktcur[t], bhist[t]);
  bcur[t] = bexcl[t];
  __syncthreads();
  for (int e = t; e < V; e += 512) {
    int i = i0 + e;
    int seg, val;
    if (i < NNZP) { seg = einc[i]; val = ninc[i]; }
    else          { seg = NN_EDGES + ninc[i - NNZP]; val = einc[i - NNZP]; }
    int bk = seg >> BKT_SHIFT;
    int slot = atomicAdd(&bcur[bk], 1);
    sval[slot] = val;
    slow[slot] = (ushort)(seg & 511);
    sbkt[slot] = (ushort)bk;
  }
  __syncthreads();
  for (int e = t; e < V; e += 512) {
    int bk = sbkt[e];
    int gpos = brun[bk] + (e - bexcl[bk]);
    bval[gpos] = sval[e];
    blow[gpos] = slow[e];
  }
}

// ---------- per-bucket placement: builds offs + final sorted list ----------
__global__ __launch_bounds__(512) void k_place(const int* __restrict__ bktbase,
                                               const int* __restrict__ bval,
                                               const ushort* __restrict__ blow,
                                               int* __restrict__ offs,
                                               int* __restrict__ list) {
  __shared__ int shist[512], sexcl[512], scur[512], wsum[8];
  __shared__ int stage[SMAX];
  const int b = blockIdx.x;
  const int t = threadIdx.x;
  const int base = bktbase[b];
  const int s = bktbase[b + 1] - base;
  shist[t] = 0;
  __syncthreads();
  for (int e = t; e < s; e += 512) atomicAdd(&shist[blow[base + e]], 1);
  __syncthreads();
  block_excl_scan_512(shist, sexcl, wsum);
  __syncthreads();
  int seg = (b << BKT_SHIFT) + t;
  if (seg < NT_SEG) offs[seg] = base + sexcl[t];
  scur[t] = sexcl[t];
  __syncthreads();
  if (s <= SMAX) {
    for (int e = t; e < s; e += 512) {
      int slot = atomicAdd(&scur[blow[base + e]], 1);
      stage[slot] = bval[base + e];
    }
    __syncthreads();
    for (int e = t; e < s; e += 512) list[base + e] = stage[e];
  } else {
    for (int e = t; e < s; e += 512) {
      int r = atomicAdd(&scur[blow[base + e]], 1);
      list[base + r] = bval[base + e];
    }
  }
}

// ---------- fp32 -> bf16 bulk convert ----------
__global__ void k_cvt(const float* __restrict__ src, ushort* __restrict__ dst, int n4) {
  int stride = gridDim.x * blockDim.x;
  for (int i = blockIdx.x * blockDim.x + threadIdx.x; i < n4; i += stride) {
    float4 v = reinterpret_cast<const float4*>(src)[i];
    ushort4 o;
    o.x = f2bf(v.x); o.y = f2bf(v.y); o.z = f2bf(v.z); o.w = f2bf(v.w);
    reinterpret_cast<ushort4*>(dst)[i] = o;
  }
}

// ---------- W fp32 [k][c] -> Wt bf16 [c][k] (both W1 and W2 in one launch) ----------
__global__ void k_wt(const float* __restrict__ W1, const float* __restrict__ W2,
                     ushort* __restrict__ W1t, ushort* __restrict__ W2t) {
  int b = blockIdx.x;                       // 64 blocks x 256
  const float* W = (b < 32) ? W1 : W2;
  ushort* Wt = (b < 32) ? W1t : W2t;
  int i = (b & 31) * 256 + threadIdx.x;     // 0..8191 -> one uint (2 bf16) each
  int c = i >> 6, k2 = (i & 63) * 2;
  float f0 = W[(size_t)k2 * DD + c];
  float f1 = W[(size_t)(k2 + 1) * DD + c];
  uint o = (uint)f2bf(f0) | ((uint)f2bf(f1) << 16);
  reinterpret_cast<uint*>(Wt)[i] = o;
}

// ---------- segment mean gather, bf16 rows, 16 lanes/segment x uint4 ----------
__global__ void k_agg(const ushort* __restrict__ src, ushort* __restrict__ dst,
                      const int* __restrict__ offs, const int* __restrict__ list,
                      int nseg, int segbase) {
  int g = (int)((blockIdx.x * blockDim.x + threadIdx.x) >> 4);
  int t = threadIdx.x & 15;
  if (g >= nseg) return;
  int b0 = offs[segbase + g];
  int b1 = offs[segbase + g + 1];
  int deg = b1 - b0;
  float acc[8];
  #pragma unroll
  for (int j = 0; j < 8; ++j) acc[j] = 0.f;
  for (int chunk = 0; chunk < deg; chunk += 16) {
    int cnt = min(16, deg - chunk);
    int myidx = (t < cnt) ? list[b0 + chunk + t] : 0;
    #pragma unroll 8
    for (int m = 0; m < cnt; ++m) {
      int id = __shfl(myidx, m, 16);
      uint4 v = reinterpret_cast<const uint4*>(src + (size_t)id * DD)[t];
      acc[0] += bf_lo(v.x); acc[1] += bf_hi(v.x);
      acc[2] += bf_lo(v.y); acc[3] += bf_hi(v.y);
      acc[4] += bf_lo(v.z); acc[5] += bf_hi(v.z);
      acc[6] += bf_lo(v.w); acc[7] += bf_hi(v.w);
    }
  }
  float inv = 1.0f / fmaxf((float)deg, 1.0f);
  uint4 o;
  o.x = (uint)f2bf(acc[0] * inv) | ((uint)f2bf(acc[1] * inv) << 16);
  o.y = (uint)f2bf(acc[2] * inv) | ((uint)f2bf(acc[3] * inv) << 16);
  o.z = (uint)f2bf(acc[4] * inv) | ((uint)f2bf(acc[5] * inv) << 16);
  o.w = (uint)f2bf(acc[6] * inv) | ((uint)f2bf(acc[7] * inv) << 16);
  reinterpret_cast<uint4*>(dst + (size_t)g * DD)[t] = o;
}

// ---------- MFMA bf16 GEMM: C[M,128] = A[M,128] @ W + gated bias, opt relu ----------
// A bf16 row-major. Wt bf16 [col][k] (pre-transposed). C fp32 or bf16. In-place safe.
template<int RELU, int CBF16>
__global__ __launch_bounds__(256) void k_gemm_mfma(
    const ushort* __restrict__ A, void* __restrict__ Cv,
    const ushort* __restrict__ Wt, const float* __restrict__ bias,
    const int* __restrict__ segoff, int M) {
  __shared__ ushort sA[DD * DD];   // 32 KB, XOR-swizzled rows (256 B each)
  __shared__ ushort sW[DD * DD];   // 32 KB, rows = output col, XOR-swizzled
  const int tid = threadIdx.x;
  const int R = blockIdx.x * DD;
  const int rows = min(DD, M - R);
  // stage Wt (linear global -> swizzled LDS), 16 B per thread-step
  for (int i = tid; i < DD * 16; i += 256) {
    int r = i >> 4, c8 = i & 15;
    uint4 v = reinterpret_cast<const uint4*>(Wt + (size_t)r * DD)[c8];
    int bo = (c8 * 16) ^ ((r & 7) << 4);
    *reinterpret_cast<uint4*>(reinterpret_cast<char*>(sW) + r * 256 + bo) = v;
  }
  // stage A tile
  for (int i = tid; i < DD * 16; i += 256) {
    int r = i >> 4, c8 = i & 15;
    uint4 v = make_uint4(0u, 0u, 0u, 0u);
    if (r < rows) v = reinterpret_cast<const uint4*>(A + (size_t)(R + r) * DD)[c8];
    int bo = (c8 * 16) ^ ((r & 7) << 4);
    *reinterpret_cast<uint4*>(reinterpret_cast<char*>(sA) + r * 256 + bo) = v;
  }
  __syncthreads();
  const int wid = tid >> 6;        // wave id 0..3, owns rows [wid*32, wid*32+32)
  const int l = tid & 63;
  const int lr = l & 15;           // row (A) / col (B) within 16-tile
  const int lg = l >> 4;           // k-group 0..3
  const int wrow = wid * 32;
  f32x4 acc[2][8];
  #pragma unroll
  for (int a = 0; a < 2; ++a)
    #pragma unroll
    for (int b = 0; b < 8; ++b) acc[a][b] = (f32x4){0.f, 0.f, 0.f, 0.f};
  const char* cA = reinterpret_cast<const char*>(sA);
  const char* cW = reinterpret_cast<const char*>(sW);
  #pragma unroll
  for (int k0 = 0; k0 < 4; ++k0) {
    int kb = k0 * 64 + lg * 16;    // byte offset of this lane's 8 bf16 in a 256 B row
    int r0 = wrow + lr, r1 = wrow + 16 + lr;
    bf16x8 a0 = *reinterpret_cast<const bf16x8*>(cA + r0 * 256 + (kb ^ ((r0 & 7) << 4)));
    bf16x8 a1 = *reinterpret_cast<const bf16x8*>(cA + r1 * 256 + (kb ^ ((r1 & 7) << 4)));
    bf16x8 bfr[8];
    #pragma unroll
    for (int ct = 0; ct < 8; ++ct) {
      int c = ct * 16 + lr;
      bfr[ct] = *reinterpret_cast<const bf16x8*>(cW + c * 256 + (kb ^ ((c & 7) << 4)));
    }
    #pragma unroll
    for (int ct = 0; ct < 8; ++ct) {
      acc[0][ct] = __builtin_amdgcn_mfma_f32_16x16x32_bf16(a0, bfr[ct], acc[0][ct], 0, 0, 0);
      acc[1][ct] = __builtin_amdgcn_mfma_f32_16x16x32_bf16(a1, bfr[ct], acc[1][ct], 0, 0, 0);
    }
  }
  // epilogue: D lane layout col = lr, row = lg*4 + j (verified C/D map)
  float bcol[8];
  #pragma unroll
  for (int ct = 0; ct < 8; ++ct) bcol[ct] = bias[ct * 16 + lr];
  #pragma unroll
  for (int rt = 0; rt < 2; ++rt) {
    #pragma unroll
    for (int j = 0; j < 4; ++j) {
      int r = wrow + rt * 16 + lg * 4 + j;
      if (r < rows) {
        int gr = R + r;
        float flag = (segoff[gr + 1] > segoff[gr]) ? 1.f : 0.f;
        #pragma unroll
        for (int ct = 0; ct < 8; ++ct) {
          float v = acc[rt][ct][j] + bcol[ct] * flag;
          if (RELU) v = fmaxf(v, 0.f);
          if (CBF16)
            reinterpret_cast<ushort*>(Cv)[(size_t)gr * DD + ct * 16 + lr] = f2bf(v);
          else
            reinterpret_cast<float*>(Cv)[(size_t)gr * DD + ct * 16 + lr] = v;
        }
      }
    }
  }
}

extern "C" void kernel_launch(void* const* d_in, const int* in_sizes, int n_in,
                              void* d_out, int out_size, void* d_ws, size_t ws_size,
                              hipStream_t stream) {
  const float* X   = (const float*)d_in[1];
  const int*   inc = (const int*)d_in[2];
  const float* W1  = (const float*)d_in[3];
  const float* b1  = (const float*)d_in[4];
  const float* W2  = (const float*)d_in[5];
  const float* b2  = (const float*)d_in[6];
  float* out = (float*)d_out;
  const int* ninc = inc;
  const int* einc = inc + NNZP;

  // workspace carve-up (~77.5 MB)
  char* wsp = (char*)d_ws;
  ushort* bufE = (ushort*)wsp; wsp += (size_t)NN_EDGES * DD * sizeof(ushort);  // 12.8 MB edge buf (in-place GEMM1)
  ushort* bufN = (ushort*)wsp; wsp += (size_t)NN_NODES * DD * sizeof(ushort);  // 25.6 MB node_raw bf16
  ushort* Xb   = (ushort*)wsp; wsp += (size_t)NN_NODES * DD * sizeof(ushort);  // 25.6 MB X bf16
  int* offs    = (int*)wsp;    wsp += (size_t)(NT_SEG + 1) * sizeof(int);
  int* list    = (int*)wsp;    wsp += (size_t)TOTP * sizeof(int);              // 12.8 MB
  int* bktcnt  = (int*)wsp;    wsp += 512 * sizeof(int);
  int* bktbase = (int*)wsp;    wsp += 512 * sizeof(int);
  int* bktcur  = (int*)wsp;    wsp += 512 * sizeof(int);
  ushort* W1t  = (ushort*)wsp; wsp += (size_t)DD * DD * sizeof(ushort);        // 32 KB
  ushort* W2t  = (ushort*)wsp; wsp += (size_t)DD * DD * sizeof(ushort);        // 32 KB
  // sort staging aliased into Xb (dead before k_cvt writes Xb)
  int* bval = (int*)Xb;                                                        // 12.8 MB
  ushort* blow = (ushort*)((char*)Xb + (size_t)TOTP * sizeof(int));            // 6.4 MB

  hipMemsetAsync(bktcnt, 0, 512 * sizeof(int), stream);

  k_bhist<<<512, 256, 0, stream>>>(ninc, einc, bktcnt);
  k_bscan<<<1, 512, 0, stream>>>(bktcnt, bktbase, bktcur, offs);
  k_bin<<<(TOTP + TILE - 1) / TILE, 512, 0, stream>>>(ninc, einc, bktcur, bval, blow);
  k_place<<<NBKT, 512, 0, stream>>>(bktbase, bval, blow, offs, list);

  k_wt<<<64, 256, 0, stream>>>(W1, W2, W1t, W2t);
  k_cvt<<<2048, 256, 0, stream>>>(X, Xb, NN_NODES * DD / 4);

  // edge_raw[e] = mean_{n in e} Xb[n]  (bf16)
  k_agg<<<(NN_EDGES * 16 + 255) / 256, 256, 0, stream>>>(Xb, bufE, offs, list, NN_EDGES, 0);
  // edge_feat = edge_raw @ W1 + b1 (deg-gated), in-place bf16, MFMA
  k_gemm_mfma<0, 1><<<(NN_EDGES + DD - 1) / DD, 256, 0, stream>>>(bufE, bufE, W1t, b1, offs, NN_EDGES);
  // node_raw[n] = mean_{e ni n} edge_feat[e]  (bf16)
  k_agg<<<(NN_NODES * 16 + 255) / 256, 256, 0, stream>>>(bufE, bufN, offs, list, NN_NODES, NN_EDGES);
  // out = relu(node_raw @ W2 + b2 (deg-gated)), fp32 to d_out, MFMA
  k_gemm_mfma<1, 0><<<(NN_NODES + DD - 1) / DD, 256, 0, stream>>>(bufN, out, W2t, b2, offs + NN_EDGES, NN_NODES);
}

// Round 5
// 232.088 us; speedup vs baseline: 3.3364x; 1.0763x over previous
//
#include <hip/hip_runtime.h>

#define NN_NODES 100000
#define NN_EDGES 50000
#define DD 128
#define NNZP 1600000
#define NT_SEG (NN_EDGES + NN_NODES)   // 150000 segments (edges first, then nodes)
#define TOTP (2 * NNZP)                // 3.2M (seg,val) pairs across both directions
#define BKT_SHIFT 9                    // 512 segments per bucket
#define NBKT ((NT_SEG + 511) / 512)    // 293
#define TILE 8192
#define SMAX 18432
#define HBLK 128                       // histogram partial blocks

typedef unsigned int uint;
typedef unsigned short ushort;
typedef __attribute__((ext_vector_type(8))) short bf16x8;
typedef __attribute__((ext_vector_type(4))) float f32x4;

__device__ __forceinline__ float bf_lo(uint u) {
  union { uint i; float f; } c; c.i = u << 16; return c.f;
}
__device__ __forceinline__ float bf_hi(uint u) {
  union { uint i; float f; } c; c.i = u & 0xffff0000u; return c.f;
}
__device__ __forceinline__ ushort f2bf(float f) {   // round-to-nearest-even
  union { float f; uint i; } c; c.f = f;
  uint r = c.i + 0x7fffu + ((c.i >> 16) & 1u);
  return (ushort)(r >> 16);
}

// ---------- exclusive block scan over 512 ints, 512 threads ----------
__device__ __forceinline__ void block_excl_scan_512(const int* __restrict__ arr,
                                                    int* __restrict__ out,
                                                    int* __restrict__ wsum) {
  int t = threadIdx.x;
  int v = arr[t];
  int lane = t & 63, wid = t >> 6;
  int s = v;
  #pragma unroll
  for (int o = 1; o < 64; o <<= 1) {
    int u = __shfl_up(s, o, 64);
    if (lane >= o) s += u;
  }
  if (lane == 63) wsum[wid] = s;
  __syncthreads();
  int add = 0;
  for (int w = 0; w < wid; ++w) add += wsum[w];
  out[t] = s + add - v;
}

// ---------- fused prep: bucket-hist partials + W transpose-convert + X->bf16 ----------
__global__ __launch_bounds__(256) void k_prep(
    const float* __restrict__ X, const int* __restrict__ ninc,
    const int* __restrict__ einc, const float* __restrict__ W1,
    const float* __restrict__ W2, ushort* __restrict__ Xb,
    ushort* __restrict__ W1t, ushort* __restrict__ W2t,
    int* __restrict__ hpart) {
  const int b = blockIdx.x;
  if (b < HBLK) {
    __shared__ int h[512];
    for (int t = threadIdx.x; t < 512; t += 256) h[t] = 0;
    __syncthreads();
    const int per = (TOTP + HBLK - 1) / HBLK;       // 25000
    const int start = b * per, end = min(TOTP, start + per);
    for (int i = start + threadIdx.x; i < end; i += 256) {
      int seg = (i < NNZP) ? einc[i] : (NN_EDGES + ninc[i - NNZP]);
      atomicAdd(&h[seg >> BKT_SHIFT], 1);
    }
    __syncthreads();
    for (int t = threadIdx.x; t < 512; t += 256) hpart[b * 512 + t] = h[t];
  } else if (b < HBLK + 64) {
    int bb = b - HBLK;
    const float* W = (bb < 32) ? W1 : W2;
    ushort* Wt = (bb < 32) ? W1t : W2t;
    int i = (bb & 31) * 256 + threadIdx.x;          // 0..8191
    int c = i >> 6, k2 = (i & 63) * 2;
    float f0 = W[(size_t)k2 * DD + c];
    float f1 = W[(size_t)(k2 + 1) * DD + c];
    reinterpret_cast<uint*>(Wt)[i] = (uint)f2bf(f0) | ((uint)f2bf(f1) << 16);
  } else {
    const int nb = gridDim.x - HBLK - 64;
    const int stride = nb * 256;
    for (int i = (b - HBLK - 64) * 256 + threadIdx.x; i < NN_NODES * DD / 4; i += stride) {
      float4 v = reinterpret_cast<const float4*>(X)[i];
      ushort4 o;
      o.x = f2bf(v.x); o.y = f2bf(v.y); o.z = f2bf(v.z); o.w = f2bf(v.w);
      reinterpret_cast<ushort4*>(Xb)[i] = o;
    }
  }
}

// ---------- bucket base scan: sum partials, exclusive scan (1 block, 512 thr) ----------
__global__ void k_bscan(const int* __restrict__ hpart, int* __restrict__ bktbase,
                        int* __restrict__ bktcur, int* __restrict__ offs) {
  __shared__ int arr[512], out[512], wsum[8];
  int t = threadIdx.x;
  int s = 0;
  for (int i = 0; i < HBLK; ++i) s += hpart[i * 512 + t];
  arr[t] = s;
  __syncthreads();
  block_excl_scan_512(arr, out, wsum);
  __syncthreads();
  bktbase[t] = out[t];
  bktcur[t] = out[t];
  if (t == 0) offs[NT_SEG] = TOTP;
}

// ---------- bin pairs into coarse buckets, single global read, coalesced runs ----------
__global__ __launch_bounds__(512) void k_bin(const int* __restrict__ ninc,
                                             const int* __restrict__ einc,
                                             int* __restrict__ bktcur,
                                             int* __restrict__ bval,
                                             ushort* __restrict__ blow) {
  __shared__ int sval[TILE];
  __shared__ ushort slow[TILE], sbkt[TILE];
  __shared__ int bhist[512], bexcl[512], bcur[512], brun[512], wsum[8];
  const int t = threadIdx.x;
  const int i0 = blockIdx.x * TILE;
  const int V = min(TILE, TOTP - i0);
  int pseg[16], pval[16];
  bhist[t] = 0;
  __syncthreads();
  #pragma unroll
  for (int j = 0; j < 16; ++j) {
    int e = t + j * 512;
    if (e < V) {
      int i = i0 + e;
      int seg, val;
      if (i < NNZP) { seg = einc[i]; val = ninc[i]; }
      else          { seg = NN_EDGES + ninc[i - NNZP]; val = einc[i - NNZP]; }
      pseg[j] = seg; pval[j] = val;
      atomicAdd(&bhist[seg >> BKT_SHIFT], 1);
    }
  }
  __syncthreads();
  block_excl_scan_512(bhist, bexcl, wsum);
  __syncthreads();
  if (t < NBKT && bhist[t] > 0) brun[t] = atomicAdd(&bktcur[t], bhist[t]);
  bcur[t] = bexcl[t];
  __syncthreads();
  #pragma unroll
  for (int j = 0; j < 16; ++j) {
    int e = t + j * 512;
    if (e < V) {
      int bk = pseg[j] >> BKT_SHIFT;
      int slot = atomicAdd(&bcur[bk], 1);
      sval[slot] = pval[j];
      slow[slot] = (ushort)(pseg[j] & 511);
      sbkt[slot] = (ushort)bk;
    }
  }
  __syncthreads();
  for (int e = t; e < V; e += 512) {
    int bk = sbkt[e];
    int gpos = brun[bk] + (e - bexcl[bk]);
    bval[gpos] = sval[e];
    blow[gpos] = slow[e];
  }
}

// ---------- per-bucket placement: builds offs + final sorted list ----------
__global__ __launch_bounds__(512) void k_place(const int* __restrict__ bktbase,
                                               const int* __restrict__ bval,
                                               const ushort* __restrict__ blow,
                                               int* __restrict__ offs,
                                               int* __restrict__ list) {
  __shared__ int shist[512], sexcl[512], scur[512], wsum[8];
  __shared__ int stage[SMAX];
  const int b = blockIdx.x;
  const int t = threadIdx.x;
  const int base = bktbase[b];
  const int s = bktbase[b + 1] - base;
  shist[t] = 0;
  __syncthreads();
  for (int e = t; e < s; e += 512) atomicAdd(&shist[blow[base + e]], 1);
  __syncthreads();
  block_excl_scan_512(shist, sexcl, wsum);
  __syncthreads();
  int seg = (b << BKT_SHIFT) + t;
  if (seg < NT_SEG) offs[seg] = base + sexcl[t];
  scur[t] = sexcl[t];
  __syncthreads();
  if (s <= SMAX) {
    for (int e = t; e < s; e += 512) {
      int slot = atomicAdd(&scur[blow[base + e]], 1);
      stage[slot] = bval[base + e];
    }
    __syncthreads();
    for (int e = t; e < s; e += 512) list[base + e] = stage[e];
  } else {
    for (int e = t; e < s; e += 512) {
      int r = atomicAdd(&scur[blow[base + e]], 1);
      list[base + r] = bval[base + e];
    }
  }
}

// ---------- segment mean gather, bf16 rows, 16 lanes/seg, 8-deep load batches ----------
__global__ __launch_bounds__(256) void k_agg(const ushort* __restrict__ src,
                                             ushort* __restrict__ dst,
                                             const int* __restrict__ offs,
                                             const int* __restrict__ list,
                                             int nseg, int segbase) {
  int g = (int)((blockIdx.x * blockDim.x + threadIdx.x) >> 4);
  int t = threadIdx.x & 15;
  if (g >= nseg) return;
  int b0 = offs[segbase + g];
  int deg = offs[segbase + g + 1] - b0;
  float acc[8];
  #pragma unroll
  for (int j = 0; j < 8; ++j) acc[j] = 0.f;
  for (int chunk = 0; chunk < deg; chunk += 16) {
    int cnt = min(16, deg - chunk);
    int myidx = (t < cnt) ? list[b0 + chunk + t] : 0;
    for (int m0 = 0; m0 < cnt; m0 += 8) {
      uint4 vb[8];
      #pragma unroll
      for (int j = 0; j < 8; ++j) {
        int id = __shfl(myidx, m0 + j, 16);
        if (m0 + j < cnt)
          vb[j] = reinterpret_cast<const uint4*>(src + (size_t)id * DD)[t];
      }
      #pragma unroll
      for (int j = 0; j < 8; ++j) {
        if (m0 + j < cnt) {
          acc[0] += bf_lo(vb[j].x); acc[1] += bf_hi(vb[j].x);
          acc[2] += bf_lo(vb[j].y); acc[3] += bf_hi(vb[j].y);
          acc[4] += bf_lo(vb[j].z); acc[5] += bf_hi(vb[j].z);
          acc[6] += bf_lo(vb[j].w); acc[7] += bf_hi(vb[j].w);
        }
      }
    }
  }
  float inv = 1.0f / fmaxf((float)deg, 1.0f);
  uint4 o;
  o.x = (uint)f2bf(acc[0] * inv) | ((uint)f2bf(acc[1] * inv) << 16);
  o.y = (uint)f2bf(acc[2] * inv) | ((uint)f2bf(acc[3] * inv) << 16);
  o.z = (uint)f2bf(acc[4] * inv) | ((uint)f2bf(acc[5] * inv) << 16);
  o.w = (uint)f2bf(acc[6] * inv) | ((uint)f2bf(acc[7] * inv) << 16);
  reinterpret_cast<uint4*>(dst + (size_t)g * DD)[t] = o;
}

// ---------- MFMA bf16 GEMM: C[M,128] = A[M,128] @ W + gated bias, opt relu ----------
template<int RELU, int CBF16>
__global__ __launch_bounds__(256) void k_gemm_mfma(
    const ushort* __restrict__ A, void* __restrict__ Cv,
    const ushort* __restrict__ Wt, const float* __restrict__ bias,
    const int* __restrict__ segoff, int M) {
  __shared__ ushort sA[DD * DD];   // 32 KB, XOR-swizzled rows (256 B each)
  __shared__ ushort sW[DD * DD];   // 32 KB, rows = output col, XOR-swizzled
  const int tid = threadIdx.x;
  const int R = blockIdx.x * DD;
  const int rows = min(DD, M - R);
  for (int i = tid; i < DD * 16; i += 256) {
    int r = i >> 4, c8 = i & 15;
    uint4 v = reinterpret_cast<const uint4*>(Wt + (size_t)r * DD)[c8];
    int bo = (c8 * 16) ^ ((r & 7) << 4);
    *reinterpret_cast<uint4*>(reinterpret_cast<char*>(sW) + r * 256 + bo) = v;
  }
  for (int i = tid; i < DD * 16; i += 256) {
    int r = i >> 4, c8 = i & 15;
    uint4 v = make_uint4(0u, 0u, 0u, 0u);
    if (r < rows) v = reinterpret_cast<const uint4*>(A + (size_t)(R + r) * DD)[c8];
    int bo = (c8 * 16) ^ ((r & 7) << 4);
    *reinterpret_cast<uint4*>(reinterpret_cast<char*>(sA) + r * 256 + bo) = v;
  }
  __syncthreads();
  const int wid = tid >> 6;
  const int l = tid & 63;
  const int lr = l & 15;
  const int lg = l >> 4;
  const int wrow = wid * 32;
  f32x4 acc[2][8];
  #pragma unroll
  for (int a = 0; a < 2; ++a)
    #pragma unroll
    for (int b = 0; b < 8; ++b) acc[a][b] = (f32x4){0.f, 0.f, 0.f, 0.f};
  const char* cA = reinterpret_cast<const char*>(sA);
  const char* cW = reinterpret_cast<const char*>(sW);
  #pragma unroll
  for (int k0 = 0; k0 < 4; ++k0) {
    int kb = k0 * 64 + lg * 16;
    int r0 = wrow + lr, r1 = wrow + 16 + lr;
    bf16x8 a0 = *reinterpret_cast<const bf16x8*>(cA + r0 * 256 + (kb ^ ((r0 & 7) << 4)));
    bf16x8 a1 = *reinterpret_cast<const bf16x8*>(cA + r1 * 256 + (kb ^ ((r1 & 7) << 4)));
    bf16x8 bfr[8];
    #pragma unroll
    for (int ct = 0; ct < 8; ++ct) {
      int c = ct * 16 + lr;
      bfr[ct] = *reinterpret_cast<const bf16x8*>(cW + c * 256 + (kb ^ ((c & 7) << 4)));
    }
    #pragma unroll
    for (int ct = 0; ct < 8; ++ct) {
      acc[0][ct] = __builtin_amdgcn_mfma_f32_16x16x32_bf16(a0, bfr[ct], acc[0][ct], 0, 0, 0);
      acc[1][ct] = __builtin_amdgcn_mfma_f32_16x16x32_bf16(a1, bfr[ct], acc[1][ct], 0, 0, 0);
    }
  }
  float bcol[8];
  #pragma unroll
  for (int ct = 0; ct < 8; ++ct) bcol[ct] = bias[ct * 16 + lr];
  #pragma unroll
  for (int rt = 0; rt < 2; ++rt) {
    #pragma unroll
    for (int j = 0; j < 4; ++j) {
      int r = wrow + rt * 16 + lg * 4 + j;
      if (r < rows) {
        int gr = R + r;
        float flag = (segoff[gr + 1] > segoff[gr]) ? 1.f : 0.f;
        #pragma unroll
        for (int ct = 0; ct < 8; ++ct) {
          float v = acc[rt][ct][j] + bcol[ct] * flag;
          if (RELU) v = fmaxf(v, 0.f);
          if (CBF16)
            reinterpret_cast<ushort*>(Cv)[(size_t)gr * DD + ct * 16 + lr] = f2bf(v);
          else
            reinterpret_cast<float*>(Cv)[(size_t)gr * DD + ct * 16 + lr] = v;
        }
      }
    }
  }
}

extern "C" void kernel_launch(void* const* d_in, const int* in_sizes, int n_in,
                              void* d_out, int out_size, void* d_ws, size_t ws_size,
                              hipStream_t stream) {
  const float* X   = (const float*)d_in[1];
  const int*   inc = (const int*)d_in[2];
  const float* W1  = (const float*)d_in[3];
  const float* b1  = (const float*)d_in[4];
  const float* W2  = (const float*)d_in[5];
  const float* b2  = (const float*)d_in[6];
  float* out = (float*)d_out;
  const int* ninc = inc;
  const int* einc = inc + NNZP;

  // workspace carve-up (~78 MB)
  char* wsp = (char*)d_ws;
  ushort* bufE = (ushort*)wsp; wsp += (size_t)NN_EDGES * DD * sizeof(ushort);  // 12.8 MB (in-place GEMM1)
  ushort* bufN = (ushort*)wsp; wsp += (size_t)NN_NODES * DD * sizeof(ushort);  // 25.6 MB node_raw bf16
  ushort* Xb   = (ushort*)wsp; wsp += (size_t)NN_NODES * DD * sizeof(ushort);  // 25.6 MB X bf16
  int* offs    = (int*)wsp;    wsp += (size_t)(NT_SEG + 1) * sizeof(int);
  int* list    = (int*)wsp;    wsp += (size_t)TOTP * sizeof(int);              // 12.8 MB
  int* hpart   = (int*)wsp;    wsp += (size_t)HBLK * 512 * sizeof(int);        // 256 KB
  int* bktbase = (int*)wsp;    wsp += 512 * sizeof(int);
  int* bktcur  = (int*)wsp;    wsp += 512 * sizeof(int);
  ushort* W1t  = (ushort*)wsp; wsp += (size_t)DD * DD * sizeof(ushort);
  ushort* W2t  = (ushort*)wsp; wsp += (size_t)DD * DD * sizeof(ushort);
  // sort staging aliased into bufN (dead before agg2 writes node_raw)
  int* bval = (int*)bufN;                                                      // 12.8 MB
  ushort* blow = (ushort*)((char*)bufN + (size_t)TOTP * sizeof(int));          // 6.4 MB

  // fused: bucket-hist partials + W1/W2 transpose->bf16 + X->bf16
  k_prep<<<HBLK + 64 + 2048, 256, 0, stream>>>(X, ninc, einc, W1, W2, Xb, W1t, W2t, hpart);
  k_bscan<<<1, 512, 0, stream>>>(hpart, bktbase, bktcur, offs);
  k_bin<<<(TOTP + TILE - 1) / TILE, 512, 0, stream>>>(ninc, einc, bktcur, bval, blow);
  k_place<<<NBKT, 512, 0, stream>>>(bktbase, bval, blow, offs, list);

  // edge_raw[e] = mean_{n in e} Xb[n]  (bf16)
  k_agg<<<(NN_EDGES * 16 + 255) / 256, 256, 0, stream>>>(Xb, bufE, offs, list, NN_EDGES, 0);
  // edge_feat = edge_raw @ W1 + b1 (deg-gated), in-place bf16, MFMA
  k_gemm_mfma<0, 1><<<(NN_EDGES + DD - 1) / DD, 256, 0, stream>>>(bufE, bufE, W1t, b1, offs, NN_EDGES);
  // node_raw[n] = mean_{e ni n} edge_feat[e]  (bf16)
  k_agg<<<(NN_NODES * 16 + 255) / 256, 256, 0, stream>>>(bufE, bufN, offs, list, NN_NODES, NN_EDGES);
  // out = relu(node_raw @ W2 + b2 (deg-gated)), fp32 to d_out, MFMA
  k_gemm_mfma<1, 0><<<(NN_NODES + DD - 1) / DD, 256, 0, stream>>>(bufN, out, W2t, b2, offs + NN_EDGES, NN_NODES);
}